// Round 25
// baseline (62.953 us; speedup 1.0000x reference)
//
#include <hip/hip_runtime.h>
#include <math.h>

#define BB 32
#define LC 512
#define LQ 64
#define HH 512

typedef __attribute__((ext_vector_type(8))) short short8;
typedef __attribute__((ext_vector_type(4))) float f32x4;

__device__ __forceinline__ unsigned short f2bf(float x) {
    unsigned int u = __float_as_uint(x);
    return (unsigned short)((u + 0x7fffu + ((u >> 16) & 1u)) >> 16);
}
__device__ __forceinline__ float bf2f(unsigned short v) {
    return __uint_as_float(((unsigned int)v) << 16);
}
__device__ __forceinline__ void nts1(float* p, float v) {
    __builtin_nontemporal_store(v, p);
}

// Kernel 1 (MFMA core, T14 async-stage split + 2-deep LDS ping-pong;
// proven fp32 epilogue verbatim; a1/e2 stored bf16; XCD swizzle) — unchanged.
__global__ __launch_bounds__(256) void s2_mfma_kernel(
    const float* __restrict__ c, const float* __restrict__ q,
    const float* __restrict__ cw, const float* __restrict__ qw,
    const float* __restrict__ cqw,
    unsigned short* __restrict__ e2, unsigned short* __restrict__ a1,
    float* __restrict__ pcm, float* __restrict__ pcs) {
    int lin = blockIdx.x + (int)gridDim.x * blockIdx.y;   // 0..255
    int swz = (lin & 7) * 32 + (lin >> 3);                // XCD-contiguous
    int it = swz & 7, b = swz >> 3;
    int i0 = it * 64;
    int t = threadIdx.x, tx = t & 15, ty = t >> 4;
    int lane = t & 63, w = t >> 6, lo = lane & 15, hi = lane >> 4;
    __shared__ __align__(16) unsigned short cmb[2][64][72];  // ping-pong [i][k] bf16
    __shared__ __align__(16) unsigned short qb[2][64][72];   // ping-pong [j][k] bf16
    __shared__ float z2s[64][65];                            // fp32 z2 tile
    __shared__ float s0_s[64], s1_s[64], mt_s[64];
    __shared__ float redm[16][65], redp[16][65];
    f32x4 acc[4] = {{0.f,0.f,0.f,0.f},{0.f,0.f,0.f,0.f},{0.f,0.f,0.f,0.f},{0.f,0.f,0.f,0.f}};
    float ps0[4] = {0.f,0.f,0.f,0.f}, ps1[4] = {0.f,0.f,0.f,0.f};

    float4 Lcv[4], Lwv[4], Lcwv[4], Lqv[4], Lqwv[4];

    #pragma unroll
    for (int u = 0; u < 4; ++u) {
        int r = u * 16 + ty;
        int h = tx * 4;
        Lcv[u]  = *(const float4*)(c + ((size_t)(b * LC + i0 + r)) * HH + h);
        Lwv[u]  = *(const float4*)(cqw + h);
        Lcwv[u] = *(const float4*)(cw + h);
        Lqv[u]  = *(const float4*)(q + ((size_t)(b * LQ + r)) * HH + h);
        Lqwv[u] = *(const float4*)(qw + h);
    }
    #pragma unroll
    for (int u = 0; u < 4; ++u) {
        int r = u * 16 + ty;
        int h = tx * 4;
        cmb[0][r][h + 0] = f2bf(Lcv[u].x * Lwv[u].x);
        cmb[0][r][h + 1] = f2bf(Lcv[u].y * Lwv[u].y);
        cmb[0][r][h + 2] = f2bf(Lcv[u].z * Lwv[u].z);
        cmb[0][r][h + 3] = f2bf(Lcv[u].w * Lwv[u].w);
        ps0[u] += Lcv[u].x * Lcwv[u].x + Lcv[u].y * Lcwv[u].y + Lcv[u].z * Lcwv[u].z + Lcv[u].w * Lcwv[u].w;
        qb[0][r][h + 0] = f2bf(Lqv[u].x);
        qb[0][r][h + 1] = f2bf(Lqv[u].y);
        qb[0][r][h + 2] = f2bf(Lqv[u].z);
        qb[0][r][h + 3] = f2bf(Lqv[u].w);
        ps1[u] += Lqv[u].x * Lqwv[u].x + Lqv[u].y * Lqwv[u].y + Lqv[u].z * Lqwv[u].z + Lqv[u].w * Lqwv[u].w;
    }

    for (int itc = 0; itc < 8; ++itc) {
        int cur = itc & 1, nxt = cur ^ 1;
        if (itc < 7) {
            int h0 = (itc + 1) * 64;
            #pragma unroll
            for (int u = 0; u < 4; ++u) {
                int r = u * 16 + ty;
                int h = tx * 4;
                Lcv[u]  = *(const float4*)(c + ((size_t)(b * LC + i0 + r)) * HH + h0 + h);
                Lwv[u]  = *(const float4*)(cqw + h0 + h);
                Lcwv[u] = *(const float4*)(cw + h0 + h);
                Lqv[u]  = *(const float4*)(q + ((size_t)(b * LQ + r)) * HH + h0 + h);
                Lqwv[u] = *(const float4*)(qw + h0 + h);
            }
        }
        __syncthreads();
        #pragma unroll
        for (int kk = 0; kk < 64; kk += 32) {
            short8 af = *(const short8*)(&cmb[cur][16 * w + lo][kk + hi * 8]);
            #pragma unroll
            for (int jt = 0; jt < 4; ++jt) {
                short8 bf = *(const short8*)(&qb[cur][16 * jt + lo][kk + hi * 8]);
                acc[jt] = __builtin_amdgcn_mfma_f32_16x16x32_bf16(af, bf, acc[jt], 0, 0, 0);
            }
        }
        if (itc < 7) {
            #pragma unroll
            for (int u = 0; u < 4; ++u) {
                int r = u * 16 + ty;
                int h = tx * 4;
                cmb[nxt][r][h + 0] = f2bf(Lcv[u].x * Lwv[u].x);
                cmb[nxt][r][h + 1] = f2bf(Lcv[u].y * Lwv[u].y);
                cmb[nxt][r][h + 2] = f2bf(Lcv[u].z * Lwv[u].z);
                cmb[nxt][r][h + 3] = f2bf(Lcv[u].w * Lwv[u].w);
                ps0[u] += Lcv[u].x * Lcwv[u].x + Lcv[u].y * Lcwv[u].y + Lcv[u].z * Lcwv[u].z + Lcv[u].w * Lcwv[u].w;
                qb[nxt][r][h + 0] = f2bf(Lqv[u].x);
                qb[nxt][r][h + 1] = f2bf(Lqv[u].y);
                qb[nxt][r][h + 2] = f2bf(Lqv[u].z);
                qb[nxt][r][h + 3] = f2bf(Lqv[u].w);
                ps1[u] += Lqv[u].x * Lqwv[u].x + Lqv[u].y * Lqwv[u].y + Lqv[u].z * Lqwv[u].z + Lqv[u].w * Lqwv[u].w;
            }
        }
    }

    #pragma unroll
    for (int jt = 0; jt < 4; ++jt)
        #pragma unroll
        for (int e = 0; e < 4; ++e)
            z2s[16 * w + hi * 4 + e][16 * jt + lo] = acc[jt][e];

    for (int off = 1; off < 16; off <<= 1) {
        #pragma unroll
        for (int u = 0; u < 4; ++u) {
            ps0[u] += __shfl_xor(ps0[u], off, 64);
            ps1[u] += __shfl_xor(ps1[u], off, 64);
        }
    }
    if (tx == 0) {
        #pragma unroll
        for (int u = 0; u < 4; ++u) {
            s0_s[u * 16 + ty] = ps0[u];
            s1_s[u * 16 + ty] = ps1[u];
        }
    }
    __syncthreads();

    float4 zacc[4];
    #pragma unroll
    for (int iy = 0; iy < 4; ++iy) zacc[iy] = *(const float4*)(&z2s[ty * 4 + iy][tx * 4]);

    float4 s1v = make_float4(s1_s[tx * 4 + 0], s1_s[tx * 4 + 1], s1_s[tx * 4 + 2], s1_s[tx * 4 + 3]);
    #pragma unroll
    for (int iy = 0; iy < 4; ++iy) {
        int gi = b * LC + i0 + ty * 4 + iy;
        float z0 = zacc[iy].x + s1v.x, z1 = zacc[iy].y + s1v.y;
        float z2v = zacc[iy].z + s1v.z, z3 = zacc[iy].w + s1v.w;
        float m = fmaxf(fmaxf(z0, z1), fmaxf(z2v, z3));
        for (int off = 1; off < 16; off <<= 1) m = fmaxf(m, __shfl_xor(m, off, 64));
        float e0 = __expf(z0 - m), e1 = __expf(z1 - m), e2v = __expf(z2v - m), e3 = __expf(z3 - m);
        float s = e0 + e1 + e2v + e3;
        for (int off = 1; off < 16; off <<= 1) s += __shfl_xor(s, off, 64);
        float si = 1.f / s;
        ushort4 av;
        av.x = f2bf(e0 * si); av.y = f2bf(e1 * si);
        av.z = f2bf(e2v * si); av.w = f2bf(e3 * si);
        *(ushort4*)(&a1[(size_t)gi * LQ + tx * 4]) = av;
    }

    float s0r[4] = {s0_s[ty * 4 + 0], s0_s[ty * 4 + 1], s0_s[ty * 4 + 2], s0_s[ty * 4 + 3]};
    #pragma unroll
    for (int jx = 0; jx < 4; ++jx) {
        float zc[4] = {(&zacc[0].x)[jx], (&zacc[1].x)[jx], (&zacc[2].x)[jx], (&zacc[3].x)[jx]};
        float m = zc[0] + s0r[0];
        m = fmaxf(m, zc[1] + s0r[1]);
        m = fmaxf(m, zc[2] + s0r[2]);
        m = fmaxf(m, zc[3] + s0r[3]);
        redm[ty][tx * 4 + jx] = m;
    }
    __syncthreads();
    if (t < 64) {
        float M = redm[0][t];
        #pragma unroll
        for (int g = 1; g < 16; ++g) M = fmaxf(M, redm[g][t]);
        mt_s[t] = M;
        pcm[(b * 8 + it) * 64 + t] = M;
    }
    __syncthreads();
    {
        float mj[4] = {mt_s[tx * 4 + 0], mt_s[tx * 4 + 1], mt_s[tx * 4 + 2], mt_s[tx * 4 + 3]};
        float colsum[4] = {0.f, 0.f, 0.f, 0.f};
        #pragma unroll
        for (int iy = 0; iy < 4; ++iy) {
            float e0 = __expf(zacc[iy].x + s0r[iy] - mj[0]);
            float e1 = __expf(zacc[iy].y + s0r[iy] - mj[1]);
            float e2v = __expf(zacc[iy].z + s0r[iy] - mj[2]);
            float e3 = __expf(zacc[iy].w + s0r[iy] - mj[3]);
            colsum[0] += e0; colsum[1] += e1; colsum[2] += e2v; colsum[3] += e3;
            int gi = b * LC + i0 + ty * 4 + iy;
            ushort4 evv;
            evv.x = f2bf(e0); evv.y = f2bf(e1); evv.z = f2bf(e2v); evv.w = f2bf(e3);
            *(ushort4*)(&e2[(size_t)gi * LQ + tx * 4]) = evv;
        }
        #pragma unroll
        for (int jx = 0; jx < 4; ++jx) redp[ty][tx * 4 + jx] = colsum[jx];
    }
    __syncthreads();
    if (t < 64) {
        float S = redp[0][t];
        #pragma unroll
        for (int g = 1; g < 16; ++g) S += redp[g][t];
        pcs[(b * 8 + it) * 64 + t] = S;
    }
}

// Kernel 2 (fused t+f, h-tile 32, XCD-swizzled; t-phase T14 ping-pong;
// f-phase: direct per-fragment nt stores, 1 barrier/chunk).
struct TFP1 { unsigned short a2b[2][64][72]; unsigned short cb[2][32][72]; };
struct TFP2 { unsigned short a1b[2][64][72]; };
union TFU { TFP1 p1; TFP2 p2; };

__global__ __launch_bounds__(256) void tf_kernel(
    const float* __restrict__ c, const float* __restrict__ q,
    const unsigned short* __restrict__ e2,
    const float* __restrict__ pcm, const float* __restrict__ pcs,
    const unsigned short* __restrict__ a1, float* __restrict__ out) {
    int lin = blockIdx.x + (int)gridDim.x * blockIdx.y;   // 0..511
    int swz = (lin & 7) * 64 + (lin >> 3);                // XCD-contiguous
    int h0 = (swz & 15) * 32, b = swz >> 4;
    int t = threadIdx.x;
    int lane = t & 63, w = t >> 6, lo = lane & 15, hi = lane >> 4;
    __shared__ __align__(16) TFU u_;
    __shared__ __align__(16) unsigned short qTb[32][72];  // [h][k] bf16
    __shared__ __align__(16) unsigned short tTb[32][72];  // [h][k] bf16 (tmat slice)
    __shared__ float sc_s[8][64];

    if (t < 64) {
        float pm[8];
        #pragma unroll
        for (int g = 0; g < 8; ++g) pm[g] = pcm[(b * 8 + g) * 64 + t];
        float M = pm[0];
        #pragma unroll
        for (int g = 1; g < 8; ++g) M = fmaxf(M, pm[g]);
        float S = 0.f, ee[8];
        #pragma unroll
        for (int g = 0; g < 8; ++g) {
            ee[g] = __expf(pm[g] - M);
            S += pcs[(b * 8 + g) * 64 + t] * ee[g];
        }
        float si = 1.f / S;
        #pragma unroll
        for (int g = 0; g < 8; ++g) sc_s[g][t] = ee[g] * si;
    }
    __syncthreads();   // sc_s visible to all (read-only below)

    // ---- t-phase: M=64 k, N=32 h, K=i; T14 ping-pong (s2-proven pattern) ----
    f32x4 acc[2] = {{0.f,0.f,0.f,0.f},{0.f,0.f,0.f,0.f}};
    float4 Lc[2];
    ushort4 Le[4];
    #pragma unroll
    for (int u = 0; u < 2; ++u) {
        int idx = u * 256 + t;
        int r = idx >> 3, h4 = (idx & 7) * 4;
        Lc[u] = *(const float4*)(c + (size_t)(b * LC + r) * HH + h0 + h4);
    }
    #pragma unroll
    for (int u = 0; u < 4; ++u) {
        int idx = u * 256 + t;
        int r = idx >> 4, k4 = (idx & 15) * 4;
        Le[u] = *(const ushort4*)(e2 + (size_t)(b * LC + r) * LQ + k4);
    }
    #pragma unroll
    for (int u = 0; u < 2; ++u) {
        int idx = u * 256 + t;
        int r = idx >> 3, h4 = (idx & 7) * 4;
        u_.p1.cb[0][h4 + 0][r] = f2bf(Lc[u].x);
        u_.p1.cb[0][h4 + 1][r] = f2bf(Lc[u].y);
        u_.p1.cb[0][h4 + 2][r] = f2bf(Lc[u].z);
        u_.p1.cb[0][h4 + 3][r] = f2bf(Lc[u].w);
    }
    #pragma unroll
    for (int u = 0; u < 4; ++u) {
        int idx = u * 256 + t;
        int r = idx >> 4, k4 = (idx & 15) * 4;
        float4 scv = *(const float4*)(&sc_s[0][k4]);
        u_.p1.a2b[0][k4 + 0][r] = f2bf(bf2f(Le[u].x) * scv.x);
        u_.p1.a2b[0][k4 + 1][r] = f2bf(bf2f(Le[u].y) * scv.y);
        u_.p1.a2b[0][k4 + 2][r] = f2bf(bf2f(Le[u].z) * scv.z);
        u_.p1.a2b[0][k4 + 3][r] = f2bf(bf2f(Le[u].w) * scv.w);
    }

    for (int icc = 0; icc < 8; ++icc) {
        int cur = icc & 1, nxt = cur ^ 1;
        if (icc < 7) {
            int ic = (icc + 1) * 64;
            #pragma unroll
            for (int u = 0; u < 2; ++u) {
                int idx = u * 256 + t;
                int r = idx >> 3, h4 = (idx & 7) * 4;
                Lc[u] = *(const float4*)(c + (size_t)(b * LC + ic + r) * HH + h0 + h4);
            }
            #pragma unroll
            for (int u = 0; u < 4; ++u) {
                int idx = u * 256 + t;
                int r = idx >> 4, k4 = (idx & 15) * 4;
                Le[u] = *(const ushort4*)(e2 + (size_t)(b * LC + ic + r) * LQ + k4);
            }
        }
        __syncthreads();   // buffers[cur] writes (prev iter / prologue) visible
        #pragma unroll
        for (int kk = 0; kk < 64; kk += 32) {
            short8 af = *(const short8*)(&u_.p1.a2b[cur][16 * w + lo][kk + hi * 8]);
            #pragma unroll
            for (int jt = 0; jt < 2; ++jt) {
                short8 bf = *(const short8*)(&u_.p1.cb[cur][16 * jt + lo][kk + hi * 8]);
                acc[jt] = __builtin_amdgcn_mfma_f32_16x16x32_bf16(af, bf, acc[jt], 0, 0, 0);
            }
        }
        if (icc < 7) {
            #pragma unroll
            for (int u = 0; u < 2; ++u) {
                int idx = u * 256 + t;
                int r = idx >> 3, h4 = (idx & 7) * 4;
                u_.p1.cb[nxt][h4 + 0][r] = f2bf(Lc[u].x);
                u_.p1.cb[nxt][h4 + 1][r] = f2bf(Lc[u].y);
                u_.p1.cb[nxt][h4 + 2][r] = f2bf(Lc[u].z);
                u_.p1.cb[nxt][h4 + 3][r] = f2bf(Lc[u].w);
            }
            #pragma unroll
            for (int u = 0; u < 4; ++u) {
                int idx = u * 256 + t;
                int r = idx >> 4, k4 = (idx & 15) * 4;
                float4 scv = *(const float4*)(&sc_s[icc + 1][k4]);
                u_.p1.a2b[nxt][k4 + 0][r] = f2bf(bf2f(Le[u].x) * scv.x);
                u_.p1.a2b[nxt][k4 + 1][r] = f2bf(bf2f(Le[u].y) * scv.y);
                u_.p1.a2b[nxt][k4 + 2][r] = f2bf(bf2f(Le[u].z) * scv.z);
                u_.p1.a2b[nxt][k4 + 3][r] = f2bf(bf2f(Le[u].w) * scv.w);
            }
        }
    }
    __syncthreads();   // t-phase MFMA reads done before a1b (overlap p1) writes below

    // spill tmat slice: D (k=16w+hi*4+e, h=16jt+lo) -> tTb[h][k]
    #pragma unroll
    for (int jt = 0; jt < 2; ++jt)
        #pragma unroll
        for (int e = 0; e < 4; ++e)
            tTb[16 * jt + lo][16 * w + hi * 4 + e] = f2bf(acc[jt][e]);
    // stage q slice -> qTb[h][k]
    #pragma unroll
    for (int u = 0; u < 2; ++u) {
        int idx = u * 256 + t;
        int k = idx >> 3, h4 = (idx & 7) * 4;
        float4 qv = *(const float4*)(q + ((size_t)(b * LQ + k)) * HH + h0 + h4);
        qTb[h4 + 0][k] = f2bf(qv.x); qTb[h4 + 1][k] = f2bf(qv.y);
        qTb[h4 + 2][k] = f2bf(qv.z); qTb[h4 + 3][k] = f2bf(qv.w);
    }
    // prologue: stage a1 chunk 0 into buffer 0
    #pragma unroll
    for (int u = 0; u < 2; ++u) {
        int idx = u * 256 + t;
        int r = idx >> 3, seg = idx & 7;
        *(short8*)(&u_.p2.a1b[0][r][seg * 8]) =
            *(const short8*)(a1 + (size_t)(b * LC + r) * LQ + seg * 8);
    }
    __syncthreads();

    // ---- f-phase: 8 i-chunks, double-buffered a1, direct nt stores, 1 barrier/chunk ----
    for (int it = 0; it < 8; ++it) {
        int cur = it & 1, nxt = cur ^ 1;
        int i0 = it * 64;
        if (it < 7) {
            #pragma unroll
            for (int u = 0; u < 2; ++u) {
                int idx = u * 256 + t;
                int r = idx >> 3, seg = idx & 7;
                *(short8*)(&u_.p2.a1b[nxt][r][seg * 8]) =
                    *(const short8*)(a1 + (size_t)(b * LC + i0 + 64 + r) * LQ + seg * 8);
            }
        }
        f32x4 fa[2] = {{0.f,0.f,0.f,0.f},{0.f,0.f,0.f,0.f}};
        f32x4 fb[2] = {{0.f,0.f,0.f,0.f},{0.f,0.f,0.f,0.f}};
        #pragma unroll
        for (int kk = 0; kk < 64; kk += 32) {
            short8 af = *(const short8*)(&u_.p2.a1b[cur][16 * w + lo][kk + hi * 8]);
            #pragma unroll
            for (int jt = 0; jt < 2; ++jt) {
                short8 bq = *(const short8*)(&qTb[16 * jt + lo][kk + hi * 8]);
                fa[jt] = __builtin_amdgcn_mfma_f32_16x16x32_bf16(af, bq, fa[jt], 0, 0, 0);
                short8 bt = *(const short8*)(&tTb[16 * jt + lo][kk + hi * 8]);
                fb[jt] = __builtin_amdgcn_mfma_f32_16x16x32_bf16(af, bt, fb[jt], 0, 0, 0);
            }
        }
        // direct per-fragment stores (validated round-13 D mapping):
        // row i = i0 + 16w + hi*4 + e, col h = h0 + 16jt + lo
        #pragma unroll
        for (int e = 0; e < 4; ++e) {
            int i = i0 + 16 * w + hi * 4 + e;
            const float* crow = c + ((size_t)(b * LC + i)) * HH + h0;
            float* orow = out + ((size_t)(b * LC + i)) * 2048 + h0;
            #pragma unroll
            for (int jt = 0; jt < 2; ++jt) {
                int h = 16 * jt + lo;
                float cv = crow[h];
                float av = fa[jt][e];
                float bv = fb[jt][e];
                nts1(orow + h, cv);
                nts1(orow + 512 + h, av);
                nts1(orow + 1024 + h, cv * av);
                nts1(orow + 1536 + h, cv * bv);
            }
        }
        __syncthreads();   // a1b[cur] safe to overwrite next iter
    }
}

extern "C" void kernel_launch(void* const* d_in, const int* in_sizes, int n_in,
                              void* d_out, int out_size, void* d_ws, size_t ws_size,
                              hipStream_t stream) {
    const float* c   = (const float*)d_in[0];
    const float* q   = (const float*)d_in[1];
    const float* cw  = (const float*)d_in[4];
    const float* qw  = (const float*)d_in[5];
    const float* cqw = (const float*)d_in[6];
    float* out = (float*)d_out;

    unsigned short* e2 = (unsigned short*)d_ws;              // 1M bf16
    unsigned short* a1 = e2 + (size_t)BB * LC * LQ;          // 1M bf16
    float* pcm = (float*)(a1 + (size_t)BB * LC * LQ);        // 16384 f32
    float* pcs = pcm + BB * (LC / 64) * LQ;                  // 16384 f32

    s2_mfma_kernel<<<dim3(LC / 64, BB), 256, 0, stream>>>(c, q, cw, qw, cqw, e2, a1, pcm, pcs);
    tf_kernel<<<dim3(HH / 32, BB), 256, 0, stream>>>(c, q, e2, pcm, pcs, a1, out);
}

// Round 26
// 51.795 us; speedup vs baseline: 1.2154x; 1.2154x over previous
//
#include <hip/hip_runtime.h>
#include <math.h>

#define BB 32
#define LC 512
#define LQ 64
#define HH 512

typedef __attribute__((ext_vector_type(8))) short short8;
typedef __attribute__((ext_vector_type(4))) float f32x4;

__device__ __forceinline__ unsigned short f2bf(float x) {
    unsigned int u = __float_as_uint(x);
    return (unsigned short)((u + 0x7fffu + ((u >> 16) & 1u)) >> 16);
}
__device__ __forceinline__ float bf2f(unsigned short v) {
    return __uint_as_float(((unsigned int)v) << 16);
}
__device__ __forceinline__ void nts(float* p, float x, float y, float z, float w) {
    f32x4 v = {x, y, z, w};
    __builtin_nontemporal_store(v, (f32x4*)p);
}

// Kernel 1 (MFMA core, T14 async-stage split + 2-deep LDS ping-pong;
// proven fp32 epilogue verbatim; a1/e2 stored bf16; XCD swizzle).
__global__ __launch_bounds__(256) void s2_mfma_kernel(
    const float* __restrict__ c, const float* __restrict__ q,
    const float* __restrict__ cw, const float* __restrict__ qw,
    const float* __restrict__ cqw,
    unsigned short* __restrict__ e2, unsigned short* __restrict__ a1,
    float* __restrict__ pcm, float* __restrict__ pcs) {
    int lin = blockIdx.x + (int)gridDim.x * blockIdx.y;   // 0..255
    int swz = (lin & 7) * 32 + (lin >> 3);                // XCD-contiguous
    int it = swz & 7, b = swz >> 3;
    int i0 = it * 64;
    int t = threadIdx.x, tx = t & 15, ty = t >> 4;
    int lane = t & 63, w = t >> 6, lo = lane & 15, hi = lane >> 4;
    __shared__ __align__(16) unsigned short cmb[2][64][72];  // ping-pong [i][k] bf16
    __shared__ __align__(16) unsigned short qb[2][64][72];   // ping-pong [j][k] bf16
    __shared__ float z2s[64][65];                            // fp32 z2 tile
    __shared__ float s0_s[64], s1_s[64], mt_s[64];
    __shared__ float redm[16][65], redp[16][65];
    f32x4 acc[4] = {{0.f,0.f,0.f,0.f},{0.f,0.f,0.f,0.f},{0.f,0.f,0.f,0.f},{0.f,0.f,0.f,0.f}};
    float ps0[4] = {0.f,0.f,0.f,0.f}, ps1[4] = {0.f,0.f,0.f,0.f};

    float4 Lcv[4], Lwv[4], Lcwv[4], Lqv[4], Lqwv[4];

    #pragma unroll
    for (int u = 0; u < 4; ++u) {
        int r = u * 16 + ty;
        int h = tx * 4;
        Lcv[u]  = *(const float4*)(c + ((size_t)(b * LC + i0 + r)) * HH + h);
        Lwv[u]  = *(const float4*)(cqw + h);
        Lcwv[u] = *(const float4*)(cw + h);
        Lqv[u]  = *(const float4*)(q + ((size_t)(b * LQ + r)) * HH + h);
        Lqwv[u] = *(const float4*)(qw + h);
    }
    #pragma unroll
    for (int u = 0; u < 4; ++u) {
        int r = u * 16 + ty;
        int h = tx * 4;
        cmb[0][r][h + 0] = f2bf(Lcv[u].x * Lwv[u].x);
        cmb[0][r][h + 1] = f2bf(Lcv[u].y * Lwv[u].y);
        cmb[0][r][h + 2] = f2bf(Lcv[u].z * Lwv[u].z);
        cmb[0][r][h + 3] = f2bf(Lcv[u].w * Lwv[u].w);
        ps0[u] += Lcv[u].x * Lcwv[u].x + Lcv[u].y * Lcwv[u].y + Lcv[u].z * Lcwv[u].z + Lcv[u].w * Lcwv[u].w;
        qb[0][r][h + 0] = f2bf(Lqv[u].x);
        qb[0][r][h + 1] = f2bf(Lqv[u].y);
        qb[0][r][h + 2] = f2bf(Lqv[u].z);
        qb[0][r][h + 3] = f2bf(Lqv[u].w);
        ps1[u] += Lqv[u].x * Lqwv[u].x + Lqv[u].y * Lqwv[u].y + Lqv[u].z * Lqwv[u].z + Lqv[u].w * Lqwv[u].w;
    }

    for (int itc = 0; itc < 8; ++itc) {
        int cur = itc & 1, nxt = cur ^ 1;
        if (itc < 7) {
            int h0 = (itc + 1) * 64;
            #pragma unroll
            for (int u = 0; u < 4; ++u) {
                int r = u * 16 + ty;
                int h = tx * 4;
                Lcv[u]  = *(const float4*)(c + ((size_t)(b * LC + i0 + r)) * HH + h0 + h);
                Lwv[u]  = *(const float4*)(cqw + h0 + h);
                Lcwv[u] = *(const float4*)(cw + h0 + h);
                Lqv[u]  = *(const float4*)(q + ((size_t)(b * LQ + r)) * HH + h0 + h);
                Lqwv[u] = *(const float4*)(qw + h0 + h);
            }
        }
        __syncthreads();
        #pragma unroll
        for (int kk = 0; kk < 64; kk += 32) {
            short8 af = *(const short8*)(&cmb[cur][16 * w + lo][kk + hi * 8]);
            #pragma unroll
            for (int jt = 0; jt < 4; ++jt) {
                short8 bf = *(const short8*)(&qb[cur][16 * jt + lo][kk + hi * 8]);
                acc[jt] = __builtin_amdgcn_mfma_f32_16x16x32_bf16(af, bf, acc[jt], 0, 0, 0);
            }
        }
        if (itc < 7) {
            #pragma unroll
            for (int u = 0; u < 4; ++u) {
                int r = u * 16 + ty;
                int h = tx * 4;
                cmb[nxt][r][h + 0] = f2bf(Lcv[u].x * Lwv[u].x);
                cmb[nxt][r][h + 1] = f2bf(Lcv[u].y * Lwv[u].y);
                cmb[nxt][r][h + 2] = f2bf(Lcv[u].z * Lwv[u].z);
                cmb[nxt][r][h + 3] = f2bf(Lcv[u].w * Lwv[u].w);
                ps0[u] += Lcv[u].x * Lcwv[u].x + Lcv[u].y * Lcwv[u].y + Lcv[u].z * Lcwv[u].z + Lcv[u].w * Lcwv[u].w;
                qb[nxt][r][h + 0] = f2bf(Lqv[u].x);
                qb[nxt][r][h + 1] = f2bf(Lqv[u].y);
                qb[nxt][r][h + 2] = f2bf(Lqv[u].z);
                qb[nxt][r][h + 3] = f2bf(Lqv[u].w);
                ps1[u] += Lqv[u].x * Lqwv[u].x + Lqv[u].y * Lqwv[u].y + Lqv[u].z * Lqwv[u].z + Lqv[u].w * Lqwv[u].w;
            }
        }
    }

    #pragma unroll
    for (int jt = 0; jt < 4; ++jt)
        #pragma unroll
        for (int e = 0; e < 4; ++e)
            z2s[16 * w + hi * 4 + e][16 * jt + lo] = acc[jt][e];

    for (int off = 1; off < 16; off <<= 1) {
        #pragma unroll
        for (int u = 0; u < 4; ++u) {
            ps0[u] += __shfl_xor(ps0[u], off, 64);
            ps1[u] += __shfl_xor(ps1[u], off, 64);
        }
    }
    if (tx == 0) {
        #pragma unroll
        for (int u = 0; u < 4; ++u) {
            s0_s[u * 16 + ty] = ps0[u];
            s1_s[u * 16 + ty] = ps1[u];
        }
    }
    __syncthreads();

    float4 zacc[4];
    #pragma unroll
    for (int iy = 0; iy < 4; ++iy) zacc[iy] = *(const float4*)(&z2s[ty * 4 + iy][tx * 4]);

    float4 s1v = make_float4(s1_s[tx * 4 + 0], s1_s[tx * 4 + 1], s1_s[tx * 4 + 2], s1_s[tx * 4 + 3]);
    #pragma unroll
    for (int iy = 0; iy < 4; ++iy) {
        int gi = b * LC + i0 + ty * 4 + iy;
        float z0 = zacc[iy].x + s1v.x, z1 = zacc[iy].y + s1v.y;
        float z2v = zacc[iy].z + s1v.z, z3 = zacc[iy].w + s1v.w;
        float m = fmaxf(fmaxf(z0, z1), fmaxf(z2v, z3));
        for (int off = 1; off < 16; off <<= 1) m = fmaxf(m, __shfl_xor(m, off, 64));
        float e0 = __expf(z0 - m), e1 = __expf(z1 - m), e2v = __expf(z2v - m), e3 = __expf(z3 - m);
        float s = e0 + e1 + e2v + e3;
        for (int off = 1; off < 16; off <<= 1) s += __shfl_xor(s, off, 64);
        float si = 1.f / s;
        ushort4 av;
        av.x = f2bf(e0 * si); av.y = f2bf(e1 * si);
        av.z = f2bf(e2v * si); av.w = f2bf(e3 * si);
        *(ushort4*)(&a1[(size_t)gi * LQ + tx * 4]) = av;
    }

    float s0r[4] = {s0_s[ty * 4 + 0], s0_s[ty * 4 + 1], s0_s[ty * 4 + 2], s0_s[ty * 4 + 3]};
    #pragma unroll
    for (int jx = 0; jx < 4; ++jx) {
        float zc[4] = {(&zacc[0].x)[jx], (&zacc[1].x)[jx], (&zacc[2].x)[jx], (&zacc[3].x)[jx]};
        float m = zc[0] + s0r[0];
        m = fmaxf(m, zc[1] + s0r[1]);
        m = fmaxf(m, zc[2] + s0r[2]);
        m = fmaxf(m, zc[3] + s0r[3]);
        redm[ty][tx * 4 + jx] = m;
    }
    __syncthreads();
    if (t < 64) {
        float M = redm[0][t];
        #pragma unroll
        for (int g = 1; g < 16; ++g) M = fmaxf(M, redm[g][t]);
        mt_s[t] = M;
        pcm[(b * 8 + it) * 64 + t] = M;
    }
    __syncthreads();
    {
        float mj[4] = {mt_s[tx * 4 + 0], mt_s[tx * 4 + 1], mt_s[tx * 4 + 2], mt_s[tx * 4 + 3]};
        float colsum[4] = {0.f, 0.f, 0.f, 0.f};
        #pragma unroll
        for (int iy = 0; iy < 4; ++iy) {
            float e0 = __expf(zacc[iy].x + s0r[iy] - mj[0]);
            float e1 = __expf(zacc[iy].y + s0r[iy] - mj[1]);
            float e2v = __expf(zacc[iy].z + s0r[iy] - mj[2]);
            float e3 = __expf(zacc[iy].w + s0r[iy] - mj[3]);
            colsum[0] += e0; colsum[1] += e1; colsum[2] += e2v; colsum[3] += e3;
            int gi = b * LC + i0 + ty * 4 + iy;
            ushort4 evv;
            evv.x = f2bf(e0); evv.y = f2bf(e1); evv.z = f2bf(e2v); evv.w = f2bf(e3);
            *(ushort4*)(&e2[(size_t)gi * LQ + tx * 4]) = evv;
        }
        #pragma unroll
        for (int jx = 0; jx < 4; ++jx) redp[ty][tx * 4 + jx] = colsum[jx];
    }
    __syncthreads();
    if (t < 64) {
        float S = redp[0][t];
        #pragma unroll
        for (int g = 1; g < 16; ++g) S += redp[g][t];
        pcs[(b * 8 + it) * 64 + t] = S;
    }
}

// Kernel 2 (fused t+f, h-tile 32, XCD-swizzled; t-phase T14 ping-pong —
// LDS-free since p2 still dominates the union).
struct TFP1 { unsigned short a2b[2][64][72]; unsigned short cb[2][32][72]; };
struct TFP2 { unsigned short a1b[2][64][72]; float spill[64][72]; };
union TFU { TFP1 p1; TFP2 p2; };

__global__ __launch_bounds__(256) void tf_kernel(
    const float* __restrict__ c, const float* __restrict__ q,
    const unsigned short* __restrict__ e2,
    const float* __restrict__ pcm, const float* __restrict__ pcs,
    const unsigned short* __restrict__ a1, float* __restrict__ out) {
    int lin = blockIdx.x + (int)gridDim.x * blockIdx.y;   // 0..511
    int swz = (lin & 7) * 64 + (lin >> 3);                // XCD-contiguous
    int h0 = (swz & 15) * 32, b = swz >> 4;
    int t = threadIdx.x;
    int lane = t & 63, w = t >> 6, lo = lane & 15, hi = lane >> 4;
    __shared__ __align__(16) TFU u_;
    __shared__ __align__(16) unsigned short qTb[32][72];  // [h][k] bf16
    __shared__ __align__(16) unsigned short tTb[32][72];  // [h][k] bf16 (tmat slice)
    __shared__ float sc_s[8][64];

    if (t < 64) {
        float pm[8];
        #pragma unroll
        for (int g = 0; g < 8; ++g) pm[g] = pcm[(b * 8 + g) * 64 + t];
        float M = pm[0];
        #pragma unroll
        for (int g = 1; g < 8; ++g) M = fmaxf(M, pm[g]);
        float S = 0.f, ee[8];
        #pragma unroll
        for (int g = 0; g < 8; ++g) {
            ee[g] = __expf(pm[g] - M);
            S += pcs[(b * 8 + g) * 64 + t] * ee[g];
        }
        float si = 1.f / S;
        #pragma unroll
        for (int g = 0; g < 8; ++g) sc_s[g][t] = ee[g] * si;
    }
    __syncthreads();   // sc_s visible to all (read-only below)

    // ---- t-phase: M=64 k, N=32 h, K=i; T14 ping-pong (s2-proven pattern) ----
    f32x4 acc[2] = {{0.f,0.f,0.f,0.f},{0.f,0.f,0.f,0.f}};
    float4 Lc[2];
    ushort4 Le[4];
    // prologue: load chunk 0 -> regs, write -> buffers[0]
    #pragma unroll
    for (int u = 0; u < 2; ++u) {
        int idx = u * 256 + t;
        int r = idx >> 3, h4 = (idx & 7) * 4;
        Lc[u] = *(const float4*)(c + (size_t)(b * LC + r) * HH + h0 + h4);
    }
    #pragma unroll
    for (int u = 0; u < 4; ++u) {
        int idx = u * 256 + t;
        int r = idx >> 4, k4 = (idx & 15) * 4;
        Le[u] = *(const ushort4*)(e2 + (size_t)(b * LC + r) * LQ + k4);
    }
    #pragma unroll
    for (int u = 0; u < 2; ++u) {
        int idx = u * 256 + t;
        int r = idx >> 3, h4 = (idx & 7) * 4;
        u_.p1.cb[0][h4 + 0][r] = f2bf(Lc[u].x);
        u_.p1.cb[0][h4 + 1][r] = f2bf(Lc[u].y);
        u_.p1.cb[0][h4 + 2][r] = f2bf(Lc[u].z);
        u_.p1.cb[0][h4 + 3][r] = f2bf(Lc[u].w);
    }
    #pragma unroll
    for (int u = 0; u < 4; ++u) {
        int idx = u * 256 + t;
        int r = idx >> 4, k4 = (idx & 15) * 4;
        float4 scv = *(const float4*)(&sc_s[0][k4]);
        u_.p1.a2b[0][k4 + 0][r] = f2bf(bf2f(Le[u].x) * scv.x);
        u_.p1.a2b[0][k4 + 1][r] = f2bf(bf2f(Le[u].y) * scv.y);
        u_.p1.a2b[0][k4 + 2][r] = f2bf(bf2f(Le[u].z) * scv.z);
        u_.p1.a2b[0][k4 + 3][r] = f2bf(bf2f(Le[u].w) * scv.w);
    }

    for (int icc = 0; icc < 8; ++icc) {
        int cur = icc & 1, nxt = cur ^ 1;
        if (icc < 7) {
            int ic = (icc + 1) * 64;
            #pragma unroll
            for (int u = 0; u < 2; ++u) {
                int idx = u * 256 + t;
                int r = idx >> 3, h4 = (idx & 7) * 4;
                Lc[u] = *(const float4*)(c + (size_t)(b * LC + ic + r) * HH + h0 + h4);
            }
            #pragma unroll
            for (int u = 0; u < 4; ++u) {
                int idx = u * 256 + t;
                int r = idx >> 4, k4 = (idx & 15) * 4;
                Le[u] = *(const ushort4*)(e2 + (size_t)(b * LC + ic + r) * LQ + k4);
            }
        }
        __syncthreads();   // buffers[cur] writes (prev iter / prologue) visible
        #pragma unroll
        for (int kk = 0; kk < 64; kk += 32) {
            short8 af = *(const short8*)(&u_.p1.a2b[cur][16 * w + lo][kk + hi * 8]);
            #pragma unroll
            for (int jt = 0; jt < 2; ++jt) {
                short8 bf = *(const short8*)(&u_.p1.cb[cur][16 * jt + lo][kk + hi * 8]);
                acc[jt] = __builtin_amdgcn_mfma_f32_16x16x32_bf16(af, bf, acc[jt], 0, 0, 0);
            }
        }
        if (icc < 7) {
            #pragma unroll
            for (int u = 0; u < 2; ++u) {
                int idx = u * 256 + t;
                int r = idx >> 3, h4 = (idx & 7) * 4;
                u_.p1.cb[nxt][h4 + 0][r] = f2bf(Lc[u].x);
                u_.p1.cb[nxt][h4 + 1][r] = f2bf(Lc[u].y);
                u_.p1.cb[nxt][h4 + 2][r] = f2bf(Lc[u].z);
                u_.p1.cb[nxt][h4 + 3][r] = f2bf(Lc[u].w);
            }
            #pragma unroll
            for (int u = 0; u < 4; ++u) {
                int idx = u * 256 + t;
                int r = idx >> 4, k4 = (idx & 15) * 4;
                float4 scv = *(const float4*)(&sc_s[icc + 1][k4]);
                u_.p1.a2b[nxt][k4 + 0][r] = f2bf(bf2f(Le[u].x) * scv.x);
                u_.p1.a2b[nxt][k4 + 1][r] = f2bf(bf2f(Le[u].y) * scv.y);
                u_.p1.a2b[nxt][k4 + 2][r] = f2bf(bf2f(Le[u].z) * scv.z);
                u_.p1.a2b[nxt][k4 + 3][r] = f2bf(bf2f(Le[u].w) * scv.w);
            }
        }
    }
    __syncthreads();   // t-phase MFMA reads done before tTb/qTb (overlap p1) writes below

    // spill tmat slice: D (k=16w+hi*4+e, h=16jt+lo) -> tTb[h][k]
    #pragma unroll
    for (int jt = 0; jt < 2; ++jt)
        #pragma unroll
        for (int e = 0; e < 4; ++e)
            tTb[16 * jt + lo][16 * w + hi * 4 + e] = f2bf(acc[jt][e]);
    // stage q slice -> qTb[h][k]
    #pragma unroll
    for (int u = 0; u < 2; ++u) {
        int idx = u * 256 + t;
        int k = idx >> 3, h4 = (idx & 7) * 4;
        float4 qv = *(const float4*)(q + ((size_t)(b * LQ + k)) * HH + h0 + h4);
        qTb[h4 + 0][k] = f2bf(qv.x); qTb[h4 + 1][k] = f2bf(qv.y);
        qTb[h4 + 2][k] = f2bf(qv.z); qTb[h4 + 3][k] = f2bf(qv.w);
    }
    // prologue: stage a1 chunk 0 into buffer 0
    #pragma unroll
    for (int u = 0; u < 2; ++u) {
        int idx = u * 256 + t;
        int r = idx >> 3, seg = idx & 7;
        *(short8*)(&u_.p2.a1b[0][r][seg * 8]) =
            *(const short8*)(a1 + (size_t)(b * LC + r) * LQ + seg * 8);
    }
    __syncthreads();

    // ---- f-phase: 8 i-chunks, double-buffered a1, 2 barriers/chunk ----
    for (int it = 0; it < 8; ++it) {
        int cur = it & 1, nxt = cur ^ 1;
        int i0 = it * 64;
        if (it < 7) {
            #pragma unroll
            for (int u = 0; u < 2; ++u) {
                int idx = u * 256 + t;
                int r = idx >> 3, seg = idx & 7;
                *(short8*)(&u_.p2.a1b[nxt][r][seg * 8]) =
                    *(const short8*)(a1 + (size_t)(b * LC + i0 + 64 + r) * LQ + seg * 8);
            }
        }
        f32x4 fa[2] = {{0.f,0.f,0.f,0.f},{0.f,0.f,0.f,0.f}};
        f32x4 fb[2] = {{0.f,0.f,0.f,0.f},{0.f,0.f,0.f,0.f}};
        #pragma unroll
        for (int kk = 0; kk < 64; kk += 32) {
            short8 af = *(const short8*)(&u_.p2.a1b[cur][16 * w + lo][kk + hi * 8]);
            #pragma unroll
            for (int jt = 0; jt < 2; ++jt) {
                short8 bq = *(const short8*)(&qTb[16 * jt + lo][kk + hi * 8]);
                fa[jt] = __builtin_amdgcn_mfma_f32_16x16x32_bf16(af, bq, fa[jt], 0, 0, 0);
                short8 bt = *(const short8*)(&tTb[16 * jt + lo][kk + hi * 8]);
                fb[jt] = __builtin_amdgcn_mfma_f32_16x16x32_bf16(af, bt, fb[jt], 0, 0, 0);
            }
        }
        // single spill: fa -> cols 0..31, fb -> cols 32..63
        #pragma unroll
        for (int jt = 0; jt < 2; ++jt)
            #pragma unroll
            for (int e = 0; e < 4; ++e) {
                u_.p2.spill[16 * w + hi * 4 + e][16 * jt + lo] = fa[jt][e];
                u_.p2.spill[16 * w + hi * 4 + e][32 + 16 * jt + lo] = fb[jt][e];
            }
        __syncthreads();
        // one store pass: all 4 sections
        #pragma unroll
        for (int u = 0; u < 2; ++u) {
            int idx = u * 256 + t;
            int r = idx >> 3, c4 = (idx & 7) * 4;
            size_t gi = (size_t)(b * LC + i0 + r);
            float4 av = *(const float4*)(&u_.p2.spill[r][c4]);
            float4 bv = *(const float4*)(&u_.p2.spill[r][32 + c4]);
            float4 cv = *(const float4*)(c + gi * HH + h0 + c4);
            float* orow = out + gi * 2048 + h0;
            nts(orow + c4, cv.x, cv.y, cv.z, cv.w);
            nts(orow + 512 + c4, av.x, av.y, av.z, av.w);
            nts(orow + 1024 + c4, cv.x * av.x, cv.y * av.y, cv.z * av.z, cv.w * av.w);
            nts(orow + 1536 + c4, cv.x * bv.x, cv.y * bv.y, cv.z * bv.z, cv.w * bv.w);
        }
        __syncthreads();   // spill + a1b[cur] safe to overwrite next iter
    }
}

extern "C" void kernel_launch(void* const* d_in, const int* in_sizes, int n_in,
                              void* d_out, int out_size, void* d_ws, size_t ws_size,
                              hipStream_t stream) {
    const float* c   = (const float*)d_in[0];
    const float* q   = (const float*)d_in[1];
    const float* cw  = (const float*)d_in[4];
    const float* qw  = (const float*)d_in[5];
    const float* cqw = (const float*)d_in[6];
    float* out = (float*)d_out;

    unsigned short* e2 = (unsigned short*)d_ws;              // 1M bf16
    unsigned short* a1 = e2 + (size_t)BB * LC * LQ;          // 1M bf16
    float* pcm = (float*)(a1 + (size_t)BB * LC * LQ);        // 16384 f32
    float* pcs = pcm + BB * (LC / 64) * LQ;                  // 16384 f32

    s2_mfma_kernel<<<dim3(LC / 64, BB), 256, 0, stream>>>(c, q, cw, qw, cqw, e2, a1, pcm, pcs);
    tf_kernel<<<dim3(HH / 32, BB), 256, 0, stream>>>(c, q, e2, pcm, pcs, a1, out);
}